// Round 6
// baseline (224.011 us; speedup 1.0000x reference)
//
#include <hip/hip_runtime.h>
#include <math.h>

#define BB 4
#define HH 8
#define NN 2048
#define DD 64
#define KTOP 16
#define CUT_MARGIN 1e-3f

typedef _Float16 half_t;
typedef __attribute__((ext_vector_type(8))) _Float16 half8;
typedef __attribute__((ext_vector_type(4))) float floatx4;

// async 16B global->LDS copy; LDS dest is wave-uniform base + lane*16,
// global src is PER-LANE (this is how the source-side swizzle works).
__device__ __forceinline__ void gl_lds16f(const float* g, float* l) {
    __builtin_amdgcn_global_load_lds(
        (const __attribute__((address_space(1))) void*)g,
        (__attribute__((address_space(3))) void*)l, 16, 0, 0);
}

// ---------------------------------------------------------------------------
// Kernel 1 (v6): L = (1/64) * sum_{h,d} q.k via f16x3 MFMA (16x16x32_f16).
// NO split kernel: stages raw fp32 q/k tiles (32KB contiguous per head) via
// global_load_lds with XOR-swizzled per-lane SOURCE (involution
// unit ^= (row&7) on 16B units, rule both-sides-or-neither), converts to
// f16 hi + f16 lo*2^11 AFTER the ds_read (scalar RTN casts == split's
// formula bit-exactly). Same HBM bytes as before (fp32 == hi+lo bytes),
// same LDS traffic, same MFMA order per accumulator -> L bit-identical.
// Serial 2-barrier loop (measured-equal-best of all schedules tried),
// 64KB LDS, 2 blocks/CU.
// ---------------------------------------------------------------------------
__global__ __launch_bounds__(256, 2) void gemm_f32stage(const float* __restrict__ q,
                                                        const float* __restrict__ kk,
                                                        float* __restrict__ L) {
    const int b  = blockIdx.z;
    const int i0 = blockIdx.y * 128;
    const int j0 = blockIdx.x * 128;
    const int tid  = threadIdx.x;
    const int wave = __builtin_amdgcn_readfirstlane(tid >> 6);
    const int lane = tid & 63;
    const int wr = wave >> 1, wc = wave & 1;
    const int lm = lane & 15, quad = lane >> 4;

    // fp32 tiles: A 128x64 (32KB) + B 128x64 (32KB) = 64KB -> 2 blocks/CU
    __shared__ __align__(16) float Asm[8192];
    __shared__ __align__(16) float Bsm[8192];

    // staging: waves 0,1 -> A halves; waves 2,3 -> B halves.
    // phys unit P = w2*1024 + i*64 + lane; source unit lin = P ^ ((P>>4)&7)
    // (XOR of row&7 into the 16B-slot bits; involution within each row-pair
    //  group; keeps each 128B line fully covered -> coalescing preserved).
    const int w2 = wave & 1;
    const float* gbase;
    float* lbase;
    if (wave < 2) { gbase = q  + ((size_t)(b * HH) * NN + i0) * DD; lbase = Asm; }
    else          { gbase = kk + ((size_t)(b * HH) * NN + j0) * DD; lbase = Bsm; }

    floatx4 acc1[4][4], acc2[4][4];
#pragma unroll
    for (int tr = 0; tr < 4; ++tr)
#pragma unroll
        for (int tc = 0; tc < 4; ++tc) {
            acc1[tr][tc] = (floatx4)0.0f;
            acc2[tr][tc] = (floatx4)0.0f;
        }

    for (int hh = 0; hh < HH; ++hh) {
        const float* gs = gbase + (size_t)hh * (NN * DD);
        __syncthreads();
#pragma unroll
        for (int i = 0; i < 16; ++i) {
            const int P   = (w2 << 10) + (i << 6) + lane;
            const int lin = (P & ~7) | ((P & 7) ^ ((i & 1) << 2) ^ quad);
            gl_lds16f(gs + (size_t)lin * 4,
                      lbase + (size_t)((w2 << 10) + (i << 6)) * 4);
        }
        __syncthreads();

#pragma unroll
        for (int ks = 0; ks < 2; ++ks) {
            half8 ah[4], al[4], bh[4], bl[4];
#pragma unroll
            for (int t = 0; t < 4; ++t) {
                // A frag: row am, cols ks*32+quad*8 .. +7 (two swizzled 16B units)
                {
                    const int am = wr * 64 + t * 16 + lm;
                    const int u0 = am * 16 + ks * 8 + quad * 2;
                    const int p0 = (u0 & ~7) | ((u0 & 7) ^ (am & 7));
                    float4 f0 = *(const float4*)&Asm[p0 * 4];
                    float4 f1 = *(const float4*)&Asm[(p0 ^ 1) * 4];
                    float a[8] = {f0.x, f0.y, f0.z, f0.w, f1.x, f1.y, f1.z, f1.w};
#pragma unroll
                    for (int e = 0; e < 8; ++e) {
                        half_t hq = (half_t)a[e];
                        ah[t][e] = hq;
                        al[t][e] = (half_t)((a[e] - (float)hq) * 2048.0f);
                    }
                }
                // B frag
                {
                    const int bm = wc * 64 + t * 16 + lm;
                    const int u0 = bm * 16 + ks * 8 + quad * 2;
                    const int p0 = (u0 & ~7) | ((u0 & 7) ^ (bm & 7));
                    float4 f0 = *(const float4*)&Bsm[p0 * 4];
                    float4 f1 = *(const float4*)&Bsm[(p0 ^ 1) * 4];
                    float a[8] = {f0.x, f0.y, f0.z, f0.w, f1.x, f1.y, f1.z, f1.w};
#pragma unroll
                    for (int e = 0; e < 8; ++e) {
                        half_t hq = (half_t)a[e];
                        bh[t][e] = hq;
                        bl[t][e] = (half_t)((a[e] - (float)hq) * 2048.0f);
                    }
                }
            }
            __builtin_amdgcn_s_setprio(1);
#pragma unroll
            for (int tr = 0; tr < 4; ++tr)
#pragma unroll
                for (int tc = 0; tc < 4; ++tc) {
                    acc1[tr][tc] = __builtin_amdgcn_mfma_f32_16x16x32_f16(
                        ah[tr], bh[tc], acc1[tr][tc], 0, 0, 0);
                    acc2[tr][tc] = __builtin_amdgcn_mfma_f32_16x16x32_f16(
                        ah[tr], bl[tc], acc2[tr][tc], 0, 0, 0);
                    acc2[tr][tc] = __builtin_amdgcn_mfma_f32_16x16x32_f16(
                        al[tr], bh[tc], acc2[tr][tc], 0, 0, 0);
                }
            __builtin_amdgcn_s_setprio(0);
        }
    }

    const float s1 = 0.015625f;
    const float s2 = 0.015625f / 2048.0f;
#pragma unroll
    for (int tr = 0; tr < 4; ++tr)
#pragma unroll
        for (int r = 0; r < 4; ++r) {
            const int grow = i0 + wr * 64 + tr * 16 + quad * 4 + r;
            float* Lp = L + ((size_t)b * NN + grow) * NN + j0 + wc * 64 + lm;
#pragma unroll
            for (int tc = 0; tc < 4; ++tc)
                Lp[tc * 16] = acc1[tr][tc][r] * s1 + acc2[tr][tc][r] * s2;
        }
}

// ---------------------------------------------------------------------------
// Kernel 2: 4 independent rows per 256-thread block (one wave each) --
// wave-local algorithm, passed with absmax 0.0. Unchanged.
// ---------------------------------------------------------------------------
__device__ __forceinline__ unsigned long long flip64(double x) {
    unsigned long long v = (unsigned long long)__double_as_longlong(x);
    return v ^ ((0ULL - (v >> 63)) | 0x8000000000000000ULL);
}
__device__ __forceinline__ double unflip64(unsigned long long k) {
    unsigned long long v = (k >> 63) ? (k ^ 0x8000000000000000ULL) : ~k;
    return __longlong_as_double((long long)v);
}

__global__ __launch_bounds__(256) void topk_mask(float* __restrict__ LM,
                                                 const float* __restrict__ u) {
    const int wave = threadIdx.x >> 6;     // 0..3 (independent rows)
    const int lane = threadIdx.x & 63;     // 0..63, one wave
    const int row  = blockIdx.x * 4 + wave;
    float* lrow = LM + (size_t)row * NN;
    const float* urow = u + (size_t)row * NN;

    __shared__ int s_idx[4][64];

    // ---- phase A: stream row, keep only z + hard bitmask ----
    float z[32];
    unsigned hard = 0;
    float4 lb = *(const float4*)(lrow + lane * 4);
    float4 ub = *(const float4*)(urow + lane * 4);
#pragma unroll
    for (int e = 0; e < 8; ++e) {
        float4 lnx, unx;
        if (e < 7) {
            lnx = *(const float4*)(lrow + (e + 1) * 256 + lane * 4);
            unx = *(const float4*)(urow + (e + 1) * 256 + lane * 4);
        }
        const float* ls = (const float*)&lb;
        const float* us = (const float*)&ub;
#pragma unroll
        for (int s = 0; s < 4; ++s) {
            float w = -__logf(us[s] + 1e-9f);
            z[e * 4 + s] = ls[s] - __logf(w + 1e-9f);
            hard |= (us[s] > 0.999f ? 1u : 0u) << (e * 4 + s);
        }
        lb = lnx; ub = unx;
    }

    // ---- phase B: cutoff = (16th largest of 64 lane-maxima) - margin ----
    float v = z[0];
#pragma unroll
    for (int r = 1; r < 32; ++r) v = fmaxf(v, z[r]);
#pragma unroll
    for (int kS = 2; kS <= 64; kS <<= 1) {
#pragma unroll
        for (int j = kS >> 1; j > 0; j >>= 1) {
            float o = __shfl_xor(v, j, 64);
            bool asc = ((lane & kS) == 0);
            bool lower = ((lane & j) == 0);
            float mn = fminf(v, o), mx = fmaxf(v, o);
            v = (asc == lower) ? mn : mx;
        }
    }
    const float cut = __shfl(v, 48, 64) - CUT_MARGIN;

    // ---- phase C: ballot-prefix candidate gather (indices only) ----
    int c = 0;
#pragma unroll
    for (int r = 0; r < 32; ++r) {
        bool p = (z[r] >= cut);
        unsigned long long m = __ballot(p);
        if (p) {
            int slot = c + __popcll(m & ((1ULL << lane) - 1ULL));
            if (slot < 64) s_idx[wave][slot] = (r >> 2) * 256 + lane * 4 + (r & 3);
        }
        c += __popcll(m);
    }
    if (c > 64) c = 64;

    // ---- phase D: f64 keys; fixed 64-wide bitonic sort (ascending);
    //      threshold = sorted lane c-16 (exact 16th-largest z64) ----
    unsigned long long key = 0xFFFFFFFFFFFFFFFFULL;
    if (lane < c) {
        int idx = s_idx[wave][lane];
        double uu = (double)urow[idx] + 1e-9;   // cache-hot gather
        double w  = -log(uu);
        double g  = -log(w + 1e-9);
        key = flip64((double)lrow[idx] + g);
    }
#pragma unroll
    for (int kS = 2; kS <= 64; kS <<= 1) {
#pragma unroll
        for (int j = kS >> 1; j > 0; j >>= 1) {
            unsigned long long o = __shfl_xor(key, j, 64);
            bool asc = ((lane & kS) == 0);
            bool lower = ((lane & j) == 0);
            unsigned long long mn = (key < o) ? key : o;
            unsigned long long mx = (key < o) ? o : key;
            key = (asc == lower) ? mn : mx;
        }
    }
    const double thresh = unflip64(__shfl(key, c - KTOP, 64));

    // ---- phase E0: band|hard elements resolved in f64 ONCE, patch z ----
    const float t_hi = (float)thresh + 3e-4f;
    const float t_lo = (float)thresh - 3e-4f;
    unsigned bm = hard;
#pragma unroll
    for (int r = 0; r < 32; ++r)
        bm |= ((z[r] <= t_hi && z[r] >= t_lo) ? 1u : 0u) << r;
    while (bm) {           // expected ~0-2 iterations per wave, sparse exec
        int t = __builtin_ctz(bm);
        bm &= bm - 1;
        const int idx = (t >> 2) * 256 + lane * 4 + (t & 3);
        double uu = (double)urow[idx] + 1e-9;
        double w  = -log(uu);
        double g  = -log(w + 1e-9);
        double z64 = (double)lrow[idx] + g;    // L still intact (no stores yet)
        z[t] = (z64 >= thresh) ? 1.0e30f : -1.0e30f;
    }

    // ---- phase E1: pure-f32 store pass ----
#pragma unroll
    for (int e = 0; e < 8; ++e) {
        float o[4];
#pragma unroll
        for (int s = 0; s < 4; ++s)
            o[s] = (z[e * 4 + s] > t_hi) ? 1.0f : 0.0f;
        *(float4*)(lrow + e * 256 + lane * 4) = *(float4*)o;
    }
}

extern "C" void kernel_launch(void* const* d_in, const int* in_sizes, int n_in,
                              void* d_out, int out_size, void* d_ws, size_t ws_size,
                              hipStream_t stream) {
    const float* q = (const float*)d_in[0];
    const float* k = (const float*)d_in[1];
    const float* u = (const float*)d_in[2];
    float* out = (float*)d_out;          // logits scratch, then final mask
    (void)d_ws; (void)ws_size;           // no workspace needed anymore

    dim3 grid1(NN / 128, NN / 128, BB);
    gemm_f32stage<<<grid1, 256, 0, stream>>>(q, k, out);

    topk_mask<<<BB * NN / 4, 256, 0, stream>>>(out, u);
}